// Round 11
// baseline (972.415 us; speedup 1.0000x reference)
//
#include <hip/hip_runtime.h>

#define TPB 256

using half4_t = __attribute__((ext_vector_type(4))) _Float16;
using half8_t = __attribute__((ext_vector_type(8))) _Float16;
using f32x4 = __attribute__((ext_vector_type(4))) float;

// ---------------- CSR build: global-atomic histogram + scan + fill ----------------
// R9 lesson: the gather is CU-request-rate bound, so the only remaining fat is
// the CSR build itself. The old atomic-free MSD counting sort (6 kernels,
// ~150-250us, scatter1 alone 42us at 6.6% occupancy) is replaced by fast
// device-scope global atomics: deg histogram -> 3-kernel scan -> fill. deg and
// cursor (400 KB) are L2-resident; csr ordering within a node is arbitrary
// (mean is order-independent).

__global__ void deg_k(const int* __restrict__ ei, int* __restrict__ deg, int E) {
  int e = blockIdx.x * TPB + threadIdx.x;
  if (e < E) atomicAdd(&deg[ei[E + e]], 1);
}

__global__ void scan1_k(const int* __restrict__ src, int* __restrict__ out,
                        int* __restrict__ chunk, int n) {
  __shared__ int sh[TPB];
  int i = blockIdx.x * TPB + threadIdx.x;
  int v = (i < n) ? src[i] : 0;
  sh[threadIdx.x] = v;
  __syncthreads();
  for (int off = 1; off < TPB; off <<= 1) {
    int t = (threadIdx.x >= off) ? sh[threadIdx.x - off] : 0;
    __syncthreads();
    sh[threadIdx.x] += t;
    __syncthreads();
  }
  if (i < n) out[i] = sh[threadIdx.x] - v;
  if (threadIdx.x == TPB - 1) chunk[blockIdx.x] = sh[TPB - 1];
}

__global__ void scan2_k(int* __restrict__ chunk, int nb) {
  __shared__ int sh[512];
  int v = (threadIdx.x < nb) ? chunk[threadIdx.x] : 0;
  sh[threadIdx.x] = v;
  __syncthreads();
  for (int off = 1; off < 512; off <<= 1) {
    int t = (threadIdx.x >= off) ? sh[threadIdx.x - off] : 0;
    __syncthreads();
    sh[threadIdx.x] += t;
    __syncthreads();
  }
  if (threadIdx.x < nb) chunk[threadIdx.x] = sh[threadIdx.x] - v;
}

// finalize: row_start += chunk; cursor = row_start; invd = 1/max(deg,1)
__global__ void scan3b_k(int* __restrict__ row_start, const int* __restrict__ chunk,
                         int* __restrict__ cursor, const int* __restrict__ deg,
                         float* __restrict__ invd, int n) {
  int i = blockIdx.x * TPB + threadIdx.x;
  if (i < n) {
    int rs = row_start[i] + chunk[blockIdx.x];
    row_start[i] = rs;
    cursor[i] = rs;
    invd[i] = 1.0f / fmaxf((float)deg[i], 1.0f);
  }
}

__global__ void fill_k(const int* __restrict__ ei, int* __restrict__ cursor,
                       int* __restrict__ csr, int E) {
  int e = blockIdx.x * TPB + threadIdx.x;
  if (e < E) {
    int s = ei[e];
    int d = ei[E + e];
    int pos = atomicAdd(&cursor[d], 1);
    csr[pos] = s;
  }
}

// ---------------- prep: zero deg + f2h(x) + weight converts + head pack ----------------

__global__ void prep_k(const float* __restrict__ x, _Float16* __restrict__ xh, int n4,
                       int* __restrict__ deg, int N,
                       const float* __restrict__ w0, const float* __restrict__ w1,
                       const float* __restrict__ w2, const float* __restrict__ w3,
                       const float* __restrict__ w4, const float* __restrict__ w5,
                       _Float16* __restrict__ wh,
                       const float* __restrict__ Wal, const float* __restrict__ War,
                       const float* __restrict__ ba, const float* __restrict__ Wsl,
                       const float* __restrict__ Wsr, const float* __restrict__ bsx,
                       const float* __restrict__ Wel, const float* __restrict__ Wer,
                       const float* __restrict__ be, _Float16* __restrict__ Wcat,
                       float* __restrict__ bcat) {
  int t = blockIdx.x * TPB + threadIdx.x;
  if (t < n4) {
    float4 v = ((const float4*)x)[t];
    half4_t o;
    o.x = (_Float16)v.x; o.y = (_Float16)v.y; o.z = (_Float16)v.z; o.w = (_Float16)v.w;
    ((half4_t*)xh)[t] = o;
  }
  if (t < N) deg[t] = 0;  // zeroed every replay, before deg_k
  if (t < 6 * 4096) {
    int which = t >> 12, i = t & 4095;
    const float* src = which == 0 ? w0 : which == 1 ? w1 : which == 2 ? w2
                     : which == 3 ? w3 : which == 4 ? w4 : w5;
    float4 v = ((const float4*)src)[i];
    half4_t o;
    o.x = (_Float16)v.x; o.y = (_Float16)v.y; o.z = (_Float16)v.z; o.w = (_Float16)v.w;
    ((half4_t*)wh)[(size_t)which * 4096 + i] = o;
  }
  if (t < 2048) {
    float v = 0.f;
    if (t < 384) v = Wal[t];
    else if (t < 640) v = Wsl[t - 384];
    else if (t < 1024) v = Wel[t - 640];
    else if (t < 1408) v = War[t - 1024];
    else if (t < 1664) v = Wsr[t - 1408];
    else v = Wer[t - 1664];
    Wcat[t] = (_Float16)v;
  }
  if (t < 16) {
    float b = 0.f;
    if (t >= 8 && t < 11) b = ba[t - 8];
    else if (t >= 11 && t < 13) b = bsx[t - 11];
    else if (t >= 13) b = be[t - 13];
    bcat[t] = b;
  }
}

// ---------------- 128-dim mean aggregation (R1/R8-verified: ~104us, 75% occ) ----------------
// At the CU vector-memory delivery roofline (~13 B/cyc/CU lane-side, R9 null).
// One wave per node. g=lane>>4 picks edge slot 0..3, l=lane&15 covers features
// l*8..l*8+7 (half8). 4 rows/instruction, 4 KB in flight, prefetched indices,
// branch-free masked tail.

__global__ __launch_bounds__(256) void agg128_k(const _Float16* __restrict__ hb,
                                                const int* __restrict__ csr,
                                                const int* __restrict__ row_start,
                                                const int* __restrict__ deg,
                                                const float* __restrict__ invd,
                                                _Float16* __restrict__ out, int n) {
  int node = (blockIdx.x << 2) + (threadIdx.x >> 6);
  if (node >= n) return;
  int lane = threadIdx.x & 63;
  int g = lane >> 4;  // edge slot 0..3
  int l = lane & 15;  // feature lane
  int s = row_start[node];
  int c = deg[node];
  const _Float16* base = hb + (l << 3);
  float a0 = 0.f, a1 = 0.f, a2 = 0.f, a3 = 0.f;
  float a4 = 0.f, a5 = 0.f, a6 = 0.f, a7 = 0.f;
  int j = 0;
  if (c >= 16) {
    int id[4];
#pragma unroll
    for (int p = 0; p < 4; ++p) id[p] = csr[s + 4 * p + g];
    while (true) {
      half8_t v[4];
#pragma unroll
      for (int p = 0; p < 4; ++p) v[p] = *(const half8_t*)&base[(size_t)id[p] * 128];
      j += 16;
      bool more = (j + 16 <= c);
      if (more) {
#pragma unroll
        for (int p = 0; p < 4; ++p) id[p] = csr[s + j + 4 * p + g];
      }
#pragma unroll
      for (int p = 0; p < 4; ++p) {
        a0 += (float)v[p][0]; a1 += (float)v[p][1];
        a2 += (float)v[p][2]; a3 += (float)v[p][3];
        a4 += (float)v[p][4]; a5 += (float)v[p][5];
        a6 += (float)v[p][6]; a7 += (float)v[p][7];
      }
      if (!more) break;
    }
  }
  if (j < c) {  // masked tail: 0..15 edges, all loads issued together
    int cm1 = c - 1;
#pragma unroll
    for (int p = 0; p < 4; ++p) {
      int e = j + 4 * p + g;
      float m = (e < c) ? 1.f : 0.f;
      int id = csr[s + min(e, cm1)];
      half8_t v = *(const half8_t*)&base[(size_t)id * 128];
      a0 = fmaf(m, (float)v[0], a0); a1 = fmaf(m, (float)v[1], a1);
      a2 = fmaf(m, (float)v[2], a2); a3 = fmaf(m, (float)v[3], a3);
      a4 = fmaf(m, (float)v[4], a4); a5 = fmaf(m, (float)v[5], a5);
      a6 = fmaf(m, (float)v[6], a6); a7 = fmaf(m, (float)v[7], a7);
    }
  }
  // reduce across the 4 edge slots (lanes l, l+16, l+32, l+48)
  a0 += __shfl_xor(a0, 16); a1 += __shfl_xor(a1, 16);
  a2 += __shfl_xor(a2, 16); a3 += __shfl_xor(a3, 16);
  a4 += __shfl_xor(a4, 16); a5 += __shfl_xor(a5, 16);
  a6 += __shfl_xor(a6, 16); a7 += __shfl_xor(a7, 16);
  a0 += __shfl_xor(a0, 32); a1 += __shfl_xor(a1, 32);
  a2 += __shfl_xor(a2, 32); a3 += __shfl_xor(a3, 32);
  a4 += __shfl_xor(a4, 32); a5 += __shfl_xor(a5, 32);
  a6 += __shfl_xor(a6, 32); a7 += __shfl_xor(a7, 32);
  if (g == 0) {
    float w = invd[node];
    half8_t r;
    r[0] = (_Float16)(a0 * w); r[1] = (_Float16)(a1 * w);
    r[2] = (_Float16)(a2 * w); r[3] = (_Float16)(a3 * w);
    r[4] = (_Float16)(a4 * w); r[5] = (_Float16)(a5 * w);
    r[6] = (_Float16)(a6 * w); r[7] = (_Float16)(a7 * w);
    *(half8_t*)&out[(size_t)node * 128 + (l << 3)] = r;
  }
}

// ---------------- dense dual GEMM: weights in LDS (XOR-swizzled), 64-row blocks ----------------
// outh = relu(Aagg@Wl^T + Ah@Wr^T + b). Block = 4 waves, 64 rows; each wave a
// 16-row strip x 128 cols (8 c-tiles of 16x16x32 f16 MFMA). Weight pair (64 KB)
// staged once per block, kc ^= row&7 swizzle. A-fragments prefetched before
// staging. C layout: col=lane&15, row=quad*4+reg.

__global__ __launch_bounds__(256) void gemm2_k(
    const _Float16* __restrict__ Aagg, const _Float16* __restrict__ Ah,
    const _Float16* __restrict__ Wh,  // [2][128][128]: Wl then Wr
    const float* __restrict__ bias, _Float16* __restrict__ outh, int n) {
  __shared__ _Float16 Ws[32768];  // 64 KB: [row 0..255][k 0..127], kc swizzled
  int tid = threadIdx.x;
  int wave = tid >> 6;
  int lane = tid & 63;
  int g = lane >> 4;
  int l = lane & 15;
  int m0 = blockIdx.x * 64 + wave * 16;
  int arow = m0 + l;
  bool valid = arow < n;

  // prefetch A fragments (issue before staging so HBM latency hides under it)
  half8_t afA[4], afH[4];
  size_t abase = (size_t)arow * 128 + g * 8;
  if (valid) {
#pragma unroll
    for (int kb = 0; kb < 4; ++kb) afA[kb] = *(const half8_t*)&Aagg[abase + kb * 32];
#pragma unroll
    for (int kb = 0; kb < 4; ++kb) afH[kb] = *(const half8_t*)&Ah[abase + kb * 32];
  } else {
#pragma unroll
    for (int kb = 0; kb < 4; ++kb) {
#pragma unroll
      for (int jj = 0; jj < 8; ++jj) { afA[kb][jj] = (_Float16)0; afH[kb][jj] = (_Float16)0; }
    }
  }

  // stage weights: 256 rows x 16 chunks of 16 B; chunk kc stored at kc^(row&7)
#pragma unroll
  for (int it = 0; it < 16; ++it) {
    int ci = tid + it * 256;        // 0..4095
    int row = ci >> 4;              // 0..255 (s*128+col)
    int kc = ci & 15;
    float4 v = *(const float4*)&Wh[(size_t)row * 128 + kc * 8];
    *(float4*)&Ws[(size_t)row * 128 + ((kc ^ (row & 7)) * 8)] = v;
  }
  __syncthreads();

  f32x4 acc[8];
#pragma unroll
  for (int ct = 0; ct < 8; ++ct) acc[ct] = (f32x4){0.f, 0.f, 0.f, 0.f};

#pragma unroll
  for (int kb = 0; kb < 4; ++kb) {
#pragma unroll
    for (int ct = 0; ct < 8; ++ct) {
      int row = ct * 16 + l;  // Wl row (s=0)
      half8_t bf = *(const half8_t*)&Ws[(size_t)row * 128 + (((kb * 4 + g) ^ (l & 7)) * 8)];
      acc[ct] = __builtin_amdgcn_mfma_f32_16x16x32_f16(afA[kb], bf, acc[ct], 0, 0, 0);
    }
  }
#pragma unroll
  for (int kb = 0; kb < 4; ++kb) {
#pragma unroll
    for (int ct = 0; ct < 8; ++ct) {
      int row = 128 + ct * 16 + l;  // Wr row (s=1)
      half8_t bf = *(const half8_t*)&Ws[(size_t)row * 128 + (((kb * 4 + g) ^ (l & 7)) * 8)];
      acc[ct] = __builtin_amdgcn_mfma_f32_16x16x32_f16(afH[kb], bf, acc[ct], 0, 0, 0);
    }
  }

#pragma unroll
  for (int ct = 0; ct < 8; ++ct) {
    int col = ct * 16 + l;
    float bc = bias[col];
#pragma unroll
    for (int r = 0; r < 4; ++r) {
      int row = m0 + g * 4 + r;
      if (row < n) {
        float v = fmaxf(acc[ct][r] + bc, 0.f);
        outh[(size_t)row * 128 + col] = (_Float16)v;
      }
    }
  }
}

// ---------------- head GEMM: [n,16] = h3 @ Wcat^T + bcat, split outputs ----------------
// head_g[n][8] = gathered-head part (32 B rows for agg8), head_r[n][8] = root.

__global__ __launch_bounds__(256) void head_gemm_k(const _Float16* __restrict__ h,
                                                   const _Float16* __restrict__ Wcat,
                                                   const float* __restrict__ bcat,
                                                   float* __restrict__ head_g,
                                                   float* __restrict__ head_r, int n) {
  __shared__ _Float16 Ws[2048];  // 16 rows x 128, kc swizzled
  __shared__ float bs[16];
  int tid = threadIdx.x;
  {
    int row = tid >> 4, kc = tid & 15;  // 256 threads = 16x16 chunks exactly
    float4 v = *(const float4*)&Wcat[(size_t)row * 128 + kc * 8];
    *(float4*)&Ws[(size_t)row * 128 + ((kc ^ (row & 7)) * 8)] = v;
    if (tid < 16) bs[tid] = bcat[tid];
  }
  __syncthreads();
  int wave = tid >> 6;
  int lane = tid & 63;
  int g = lane >> 4;
  int l = lane & 15;
  int m0 = blockIdx.x * 64 + wave * 16;
  int arow = m0 + l;
  bool valid = arow < n;
  size_t abase = (size_t)arow * 128 + g * 8;
  f32x4 acc = (f32x4){0.f, 0.f, 0.f, 0.f};
#pragma unroll
  for (int kb = 0; kb < 4; ++kb) {
    half8_t af;
    if (valid) {
      af = *(const half8_t*)&h[abase + kb * 32];
    } else {
#pragma unroll
      for (int jj = 0; jj < 8; ++jj) af[jj] = (_Float16)0;
    }
    half8_t bf = *(const half8_t*)&Ws[(size_t)l * 128 + (((kb * 4 + g) ^ (l & 7)) * 8)];
    acc = __builtin_amdgcn_mfma_f32_16x16x32_f16(af, bf, acc, 0, 0, 0);
  }
  float bc = bs[l];
#pragma unroll
  for (int r = 0; r < 4; ++r) {
    int row = m0 + g * 4 + r;
    if (row < n) {
      float v = acc[r] + bc;
      if (l < 8) head_g[(size_t)row * 8 + l] = v;
      else head_r[(size_t)row * 8 + (l - 8)] = v;
    }
  }
}

// ---------------- 8-dim aggregation + output write ----------------
// out layout: age [n,3] @0, sex [n,2] @3n, eth [n,3] @5n
// head_g rows are 32 B: half the random-gather line traffic of [n,16].

__global__ void agg8_k(const float* __restrict__ head_g, const float* __restrict__ head_r,
                       const int* __restrict__ csr, const int* __restrict__ row_start,
                       const int* __restrict__ deg, const float* __restrict__ invd,
                       float* __restrict__ out, int n) {
  int node = (blockIdx.x << 2) + (threadIdx.x >> 6);
  if (node >= n) return;
  int lane = threadIdx.x & 63;
  int c2 = lane & 3;  // feature pair
  int g = lane >> 2;  // edge slot 0..15
  int s = row_start[node], cnt = deg[node];
  float ax = 0.f, ay = 0.f;
  int j = 0;
  for (; j + 32 <= cnt; j += 32) {
#pragma unroll
    for (int p = 0; p < 2; ++p) {
      int id = csr[s + j + 16 * p + g];
      float2 v = *(const float2*)&head_g[(size_t)id * 8 + 2 * c2];
      ax += v.x;
      ay += v.y;
    }
  }
  if (j < cnt) {
    int cm1 = cnt - 1;
#pragma unroll
    for (int p = 0; p < 2; ++p) {
      int e = j + 16 * p + g;
      float m = (e < cnt) ? 1.f : 0.f;
      int id = csr[s + min(e, cm1)];
      float2 v = *(const float2*)&head_g[(size_t)id * 8 + 2 * c2];
      ax = fmaf(m, v.x, ax);
      ay = fmaf(m, v.y, ay);
    }
  }
  ax += __shfl_xor(ax, 4);  ay += __shfl_xor(ay, 4);
  ax += __shfl_xor(ax, 8);  ay += __shfl_xor(ay, 8);
  ax += __shfl_xor(ax, 16); ay += __shfl_xor(ay, 16);
  ax += __shfl_xor(ax, 32); ay += __shfl_xor(ay, 32);
  if (g == 0) {
    float w = invd[node];
    float r0 = ax * w + head_r[(size_t)node * 8 + 2 * c2];
    float r1 = ay * w + head_r[(size_t)node * 8 + 2 * c2 + 1];
    float rr[2] = {r0, r1};
#pragma unroll
    for (int q = 0; q < 2; ++q) {
      int f = 2 * c2 + q;
      float r = rr[q];
      if (f < 3) out[(size_t)node * 3 + f] = r;
      else if (f < 5) out[(size_t)3 * n + (size_t)node * 2 + (f - 3)] = r;
      else out[(size_t)5 * n + (size_t)node * 3 + (f - 5)] = r;
    }
  }
}

// ---------------- launch ----------------

extern "C" void kernel_launch(void* const* d_in, const int* in_sizes, int n_in,
                              void* d_out, int out_size, void* d_ws, size_t ws_size,
                              hipStream_t stream) {
  const float* x = (const float*)d_in[0];
  const int* ei = (const int*)d_in[1];
  const float* W1l = (const float*)d_in[2];
  const float* W1r = (const float*)d_in[3];
  const float* b1 = (const float*)d_in[4];
  const float* W2l = (const float*)d_in[5];
  const float* W2r = (const float*)d_in[6];
  const float* b2 = (const float*)d_in[7];
  const float* W3l = (const float*)d_in[8];
  const float* W3r = (const float*)d_in[9];
  const float* b3 = (const float*)d_in[10];
  const float* Wal = (const float*)d_in[11];
  const float* War = (const float*)d_in[12];
  const float* ba = (const float*)d_in[13];
  const float* Wsl = (const float*)d_in[14];
  const float* Wsr = (const float*)d_in[15];
  const float* bsx = (const float*)d_in[16];
  const float* Wel = (const float*)d_in[17];
  const float* Wer = (const float*)d_in[18];
  const float* be = (const float*)d_in[19];

  int N = in_sizes[0] / 128;
  int E = in_sizes[1] / 2;

  char* w = (char*)d_ws;
  auto alloc = [&](size_t b) {
    char* p = w;
    w += (b + 255) & ~(size_t)255;
    return p;
  };
  int* deg = (int*)alloc((size_t)N * 4);
  int* row_start = (int*)alloc((size_t)N * 4);
  int* cursor = (int*)alloc((size_t)N * 4);
  float* invd = (float*)alloc((size_t)N * 4);
  int* chunk = (int*)alloc(512 * 4);
  int* csr = (int*)alloc((size_t)E * 4);
  _Float16* xh = (_Float16*)alloc((size_t)N * 128 * 2);
  _Float16* aggh = (_Float16*)alloc((size_t)N * 128 * 2);
  _Float16* hA = (_Float16*)alloc((size_t)N * 128 * 2);
  _Float16* hB = (_Float16*)alloc((size_t)N * 128 * 2);
  _Float16* wh = (_Float16*)alloc((size_t)6 * 16384 * 2);
  _Float16* Wcat = (_Float16*)alloc(2048 * 2);
  float* bcat = (float*)alloc(16 * 4);
  float* head_g = (float*)alloc((size_t)N * 8 * 4);
  float* head_r = (float*)alloc((size_t)N * 8 * 4);

  int nbNode = (N + 3) / 4;
  int nbM = (N + 63) / 64;
  int nbC = (N * 32 + TPB - 1) / TPB;
  int nbE = (E + TPB - 1) / TPB;
  int nbScan = (N + TPB - 1) / TPB;  // 391 <= 512: scan2 single block OK

  // prep zeroes deg and converts inputs (must precede deg_k)
  prep_k<<<nbC, TPB, 0, stream>>>(x, xh, N * 32, deg, N, W1l, W1r, W2l, W2r, W3l, W3r,
                                  wh, Wal, War, ba, Wsl, Wsr, bsx, Wel, Wer, be, Wcat,
                                  bcat);
  // CSR build via global atomics
  deg_k<<<nbE, TPB, 0, stream>>>(ei, deg, E);
  scan1_k<<<nbScan, TPB, 0, stream>>>(deg, row_start, chunk, N);
  scan2_k<<<1, 512, 0, stream>>>(chunk, nbScan);
  scan3b_k<<<nbScan, TPB, 0, stream>>>(row_start, chunk, cursor, deg, invd, N);
  fill_k<<<nbE, TPB, 0, stream>>>(ei, cursor, csr, E);

  // layer 1: x -> hA
  agg128_k<<<nbNode, TPB, 0, stream>>>(xh, csr, row_start, deg, invd, aggh, N);
  gemm2_k<<<nbM, TPB, 0, stream>>>(aggh, xh, wh + 0 * 16384, b1, hA, N);
  // layer 2: hA -> hB
  agg128_k<<<nbNode, TPB, 0, stream>>>(hA, csr, row_start, deg, invd, aggh, N);
  gemm2_k<<<nbM, TPB, 0, stream>>>(aggh, hA, wh + 2 * 16384, b2, hB, N);
  // layer 3: hB -> hA
  agg128_k<<<nbNode, TPB, 0, stream>>>(hB, csr, row_start, deg, invd, aggh, N);
  gemm2_k<<<nbM, TPB, 0, stream>>>(aggh, hB, wh + 4 * 16384, b3, hA, N);
  // heads: transform to split 8+8 layout, then aggregate
  head_gemm_k<<<nbM, TPB, 0, stream>>>(hA, Wcat, bcat, head_g, head_r, N);
  agg8_k<<<nbNode, TPB, 0, stream>>>(head_g, head_r, csr, row_start, deg, invd,
                                     (float*)d_out, N);
}

// Round 12
// 684.151 us; speedup vs baseline: 1.4213x; 1.4213x over previous
//
#include <hip/hip_runtime.h>

#define TPB 256
#define NB1 1024   // stripe blocks for edge passes (256 starved: 1 block/CU, 6.6% occ)
#define NBUCK 512  // coarse buckets (dst>>8); supports N <= 131072

using half4_t = __attribute__((ext_vector_type(4))) _Float16;
using half8_t = __attribute__((ext_vector_type(8))) _Float16;
using f32x4 = __attribute__((ext_vector_type(4))) float;

// ---------------- CSR build: atomic-free MSD counting sort ----------------
// R11 lesson: global-atomic fill_k = 289us (194 MB write-amp from random 4B
// stores + LLC atomic serialization). The counting sort's contiguous
// LDS-staged writes are the right algorithm; its deficiency was grid
// starvation (NB1=256 = 1 block/CU). Widened to NB1=1024 + 512-thread build_k.

__global__ __launch_bounds__(256) void hist1_k(const int* __restrict__ ei,
                                               int* __restrict__ hist, int E, int stripe) {
  __shared__ int h[NBUCK];
  for (int i = threadIdx.x; i < NBUCK; i += 256) h[i] = 0;
  __syncthreads();
  int b0 = blockIdx.x * stripe;
  int b1 = min(b0 + stripe, E);
  for (int e = b0 + threadIdx.x; e < b1; e += 256) atomicAdd(&h[ei[E + e] >> 8], 1);
  __syncthreads();
  for (int i = threadIdx.x; i < NBUCK; i += 256) hist[i * NB1 + blockIdx.x] = h[i];
}

__global__ void scan1_k(const int* __restrict__ src, int* __restrict__ out,
                        int* __restrict__ chunk, int n) {
  __shared__ int sh[TPB];
  int i = blockIdx.x * TPB + threadIdx.x;
  int v = (i < n) ? src[i] : 0;
  sh[threadIdx.x] = v;
  __syncthreads();
  for (int off = 1; off < TPB; off <<= 1) {
    int t = (threadIdx.x >= off) ? sh[threadIdx.x - off] : 0;
    __syncthreads();
    sh[threadIdx.x] += t;
    __syncthreads();
  }
  if (i < n) out[i] = sh[threadIdx.x] - v;
  if (threadIdx.x == TPB - 1) chunk[blockIdx.x] = sh[TPB - 1];
}

// generic middle scan: 512 threads x SEQ=4 sequential -> supports nb <= 2048
__global__ void scan2_k(int* __restrict__ chunk, int nb) {
  __shared__ int sh[512];
  int t = threadIdx.x;
  int base = t * 4;
  int local[4];
  int sum = 0;
#pragma unroll
  for (int k = 0; k < 4; ++k) {
    int idx = base + k;
    int v = (idx < nb) ? chunk[idx] : 0;
    local[k] = sum;
    sum += v;
  }
  sh[t] = sum;
  __syncthreads();
  for (int off = 1; off < 512; off <<= 1) {
    int tv = (t >= off) ? sh[t - off] : 0;
    __syncthreads();
    sh[t] += tv;
    __syncthreads();
  }
  int ex = sh[t] - sum;
#pragma unroll
  for (int k = 0; k < 4; ++k) {
    int idx = base + k;
    if (idx < nb) chunk[idx] = ex + local[k];
  }
}

__global__ void scan3_k(int* __restrict__ out, const int* __restrict__ chunk, int n) {
  int i = blockIdx.x * TPB + threadIdx.x;
  if (i < n) out[i] += chunk[blockIdx.x];
}

// pack: src (24 bits) | low8(dst) << 24
__global__ __launch_bounds__(256) void scatter1_k(const int* __restrict__ ei,
                                                  const int* __restrict__ base,
                                                  unsigned* __restrict__ ebuf, int E,
                                                  int stripe) {
  __shared__ int cur[NBUCK];
  for (int i = threadIdx.x; i < NBUCK; i += 256) cur[i] = base[i * NB1 + blockIdx.x];
  __syncthreads();
  int b0 = blockIdx.x * stripe;
  int b1 = min(b0 + stripe, E);
  for (int e = b0 + threadIdx.x; e < b1; e += 256) {
    int s = ei[e];
    int d = ei[E + e];
    int p = atomicAdd(&cur[d >> 8], 1);
    ebuf[p] = (unsigned)s | ((unsigned)(d & 255) << 24);
  }
}

// 512 threads: both edge passes run 2x wider; 256-entry scan guards t<256.
__global__ __launch_bounds__(512) void build_k(const unsigned* __restrict__ ebuf,
                                               const int* __restrict__ base,
                                               int* __restrict__ row_start,
                                               int* __restrict__ deg,
                                               float* __restrict__ invd,
                                               int* __restrict__ csr, int N, int E) {
  __shared__ int h[256];
  __shared__ int excl[256];
  __shared__ int bse[2];
  int b = blockIdx.x;
  int t = threadIdx.x;
  if (t == 0) {
    bse[0] = base[b * NB1];
    bse[1] = (b + 1 < NBUCK) ? base[(b + 1) * NB1] : E;
  }
  if (t < 256) h[t] = 0;
  __syncthreads();
  int bs = bse[0], be = bse[1];
  for (int e = bs + t; e < be; e += 512) atomicAdd(&h[ebuf[e] >> 24], 1);
  __syncthreads();
  int v = 0;
  if (t < 256) {
    v = h[t];
    excl[t] = v;
  }
  __syncthreads();
  for (int off = 1; off < 256; off <<= 1) {
    int tv = (t >= off && t < 256) ? excl[t - off] : 0;
    __syncthreads();
    if (t < 256) excl[t] += tv;
    __syncthreads();
  }
  if (t < 256) {
    int ex = excl[t] - v;
    int node = b * 256 + t;
    if (node < N) {
      row_start[node] = bs + ex;
      deg[node] = v;
      invd[node] = 1.0f / fmaxf((float)v, 1.0f);
    }
    h[t] = bs + ex;
  }
  __syncthreads();
  for (int e = bs + t; e < be; e += 512) {
    unsigned p = ebuf[e];
    int pos = atomicAdd(&h[p >> 24], 1);
    csr[pos] = (int)(p & 0xFFFFFFu);
  }
}

// ---------------- prep: f2h(x) + weight converts + head pack ----------------

__global__ void prep_k(const float* __restrict__ x, _Float16* __restrict__ xh, int n4,
                       const float* __restrict__ w0, const float* __restrict__ w1,
                       const float* __restrict__ w2, const float* __restrict__ w3,
                       const float* __restrict__ w4, const float* __restrict__ w5,
                       _Float16* __restrict__ wh,
                       const float* __restrict__ Wal, const float* __restrict__ War,
                       const float* __restrict__ ba, const float* __restrict__ Wsl,
                       const float* __restrict__ Wsr, const float* __restrict__ bsx,
                       const float* __restrict__ Wel, const float* __restrict__ Wer,
                       const float* __restrict__ be, _Float16* __restrict__ Wcat,
                       float* __restrict__ bcat) {
  int t = blockIdx.x * TPB + threadIdx.x;
  if (t < n4) {
    float4 v = ((const float4*)x)[t];
    half4_t o;
    o.x = (_Float16)v.x; o.y = (_Float16)v.y; o.z = (_Float16)v.z; o.w = (_Float16)v.w;
    ((half4_t*)xh)[t] = o;
  }
  if (t < 6 * 4096) {
    int which = t >> 12, i = t & 4095;
    const float* src = which == 0 ? w0 : which == 1 ? w1 : which == 2 ? w2
                     : which == 3 ? w3 : which == 4 ? w4 : w5;
    float4 v = ((const float4*)src)[i];
    half4_t o;
    o.x = (_Float16)v.x; o.y = (_Float16)v.y; o.z = (_Float16)v.z; o.w = (_Float16)v.w;
    ((half4_t*)wh)[(size_t)which * 4096 + i] = o;
  }
  if (t < 2048) {
    float v = 0.f;
    if (t < 384) v = Wal[t];
    else if (t < 640) v = Wsl[t - 384];
    else if (t < 1024) v = Wel[t - 640];
    else if (t < 1408) v = War[t - 1024];
    else if (t < 1664) v = Wsr[t - 1408];
    else v = Wer[t - 1664];
    Wcat[t] = (_Float16)v;
  }
  if (t < 16) {
    float b = 0.f;
    if (t >= 8 && t < 11) b = ba[t - 8];
    else if (t >= 11 && t < 13) b = bsx[t - 11];
    else if (t >= 13) b = be[t - 13];
    bcat[t] = b;
  }
}

// ---------------- 128-dim mean aggregation (R1/R8-verified: ~104us, 75% occ) ----------------
// At the CU vector-memory delivery roofline (~13 B/cyc/CU lane-side; R9 null
// confirmed the wall is request/delivery rate, not LLC traffic).

__global__ __launch_bounds__(256) void agg128_k(const _Float16* __restrict__ hb,
                                                const int* __restrict__ csr,
                                                const int* __restrict__ row_start,
                                                const int* __restrict__ deg,
                                                const float* __restrict__ invd,
                                                _Float16* __restrict__ out, int n) {
  int node = (blockIdx.x << 2) + (threadIdx.x >> 6);
  if (node >= n) return;
  int lane = threadIdx.x & 63;
  int g = lane >> 4;  // edge slot 0..3
  int l = lane & 15;  // feature lane
  int s = row_start[node];
  int c = deg[node];
  const _Float16* base = hb + (l << 3);
  float a0 = 0.f, a1 = 0.f, a2 = 0.f, a3 = 0.f;
  float a4 = 0.f, a5 = 0.f, a6 = 0.f, a7 = 0.f;
  int j = 0;
  if (c >= 16) {
    int id[4];
#pragma unroll
    for (int p = 0; p < 4; ++p) id[p] = csr[s + 4 * p + g];
    while (true) {
      half8_t v[4];
#pragma unroll
      for (int p = 0; p < 4; ++p) v[p] = *(const half8_t*)&base[(size_t)id[p] * 128];
      j += 16;
      bool more = (j + 16 <= c);
      if (more) {
#pragma unroll
        for (int p = 0; p < 4; ++p) id[p] = csr[s + j + 4 * p + g];
      }
#pragma unroll
      for (int p = 0; p < 4; ++p) {
        a0 += (float)v[p][0]; a1 += (float)v[p][1];
        a2 += (float)v[p][2]; a3 += (float)v[p][3];
        a4 += (float)v[p][4]; a5 += (float)v[p][5];
        a6 += (float)v[p][6]; a7 += (float)v[p][7];
      }
      if (!more) break;
    }
  }
  if (j < c) {  // masked tail: 0..15 edges, all loads issued together
    int cm1 = c - 1;
#pragma unroll
    for (int p = 0; p < 4; ++p) {
      int e = j + 4 * p + g;
      float m = (e < c) ? 1.f : 0.f;
      int id = csr[s + min(e, cm1)];
      half8_t v = *(const half8_t*)&base[(size_t)id * 128];
      a0 = fmaf(m, (float)v[0], a0); a1 = fmaf(m, (float)v[1], a1);
      a2 = fmaf(m, (float)v[2], a2); a3 = fmaf(m, (float)v[3], a3);
      a4 = fmaf(m, (float)v[4], a4); a5 = fmaf(m, (float)v[5], a5);
      a6 = fmaf(m, (float)v[6], a6); a7 = fmaf(m, (float)v[7], a7);
    }
  }
  // reduce across the 4 edge slots (lanes l, l+16, l+32, l+48)
  a0 += __shfl_xor(a0, 16); a1 += __shfl_xor(a1, 16);
  a2 += __shfl_xor(a2, 16); a3 += __shfl_xor(a3, 16);
  a4 += __shfl_xor(a4, 16); a5 += __shfl_xor(a5, 16);
  a6 += __shfl_xor(a6, 16); a7 += __shfl_xor(a7, 16);
  a0 += __shfl_xor(a0, 32); a1 += __shfl_xor(a1, 32);
  a2 += __shfl_xor(a2, 32); a3 += __shfl_xor(a3, 32);
  a4 += __shfl_xor(a4, 32); a5 += __shfl_xor(a5, 32);
  a6 += __shfl_xor(a6, 32); a7 += __shfl_xor(a7, 32);
  if (g == 0) {
    float w = invd[node];
    half8_t r;
    r[0] = (_Float16)(a0 * w); r[1] = (_Float16)(a1 * w);
    r[2] = (_Float16)(a2 * w); r[3] = (_Float16)(a3 * w);
    r[4] = (_Float16)(a4 * w); r[5] = (_Float16)(a5 * w);
    r[6] = (_Float16)(a6 * w); r[7] = (_Float16)(a7 * w);
    *(half8_t*)&out[(size_t)node * 128 + (l << 3)] = r;
  }
}

// ---------------- dense dual GEMM: weights in LDS (XOR-swizzled), 64-row blocks ----------------

__global__ __launch_bounds__(256) void gemm2_k(
    const _Float16* __restrict__ Aagg, const _Float16* __restrict__ Ah,
    const _Float16* __restrict__ Wh,  // [2][128][128]: Wl then Wr
    const float* __restrict__ bias, _Float16* __restrict__ outh, int n) {
  __shared__ _Float16 Ws[32768];  // 64 KB: [row 0..255][k 0..127], kc swizzled
  int tid = threadIdx.x;
  int wave = tid >> 6;
  int lane = tid & 63;
  int g = lane >> 4;
  int l = lane & 15;
  int m0 = blockIdx.x * 64 + wave * 16;
  int arow = m0 + l;
  bool valid = arow < n;

  // prefetch A fragments (issue before staging so HBM latency hides under it)
  half8_t afA[4], afH[4];
  size_t abase = (size_t)arow * 128 + g * 8;
  if (valid) {
#pragma unroll
    for (int kb = 0; kb < 4; ++kb) afA[kb] = *(const half8_t*)&Aagg[abase + kb * 32];
#pragma unroll
    for (int kb = 0; kb < 4; ++kb) afH[kb] = *(const half8_t*)&Ah[abase + kb * 32];
  } else {
#pragma unroll
    for (int kb = 0; kb < 4; ++kb) {
#pragma unroll
      for (int jj = 0; jj < 8; ++jj) { afA[kb][jj] = (_Float16)0; afH[kb][jj] = (_Float16)0; }
    }
  }

  // stage weights: 256 rows x 16 chunks of 16 B; chunk kc stored at kc^(row&7)
#pragma unroll
  for (int it = 0; it < 16; ++it) {
    int ci = tid + it * 256;        // 0..4095
    int row = ci >> 4;              // 0..255 (s*128+col)
    int kc = ci & 15;
    float4 v = *(const float4*)&Wh[(size_t)row * 128 + kc * 8];
    *(float4*)&Ws[(size_t)row * 128 + ((kc ^ (row & 7)) * 8)] = v;
  }
  __syncthreads();

  f32x4 acc[8];
#pragma unroll
  for (int ct = 0; ct < 8; ++ct) acc[ct] = (f32x4){0.f, 0.f, 0.f, 0.f};

#pragma unroll
  for (int kb = 0; kb < 4; ++kb) {
#pragma unroll
    for (int ct = 0; ct < 8; ++ct) {
      int row = ct * 16 + l;  // Wl row (s=0)
      half8_t bf = *(const half8_t*)&Ws[(size_t)row * 128 + (((kb * 4 + g) ^ (l & 7)) * 8)];
      acc[ct] = __builtin_amdgcn_mfma_f32_16x16x32_f16(afA[kb], bf, acc[ct], 0, 0, 0);
    }
  }
#pragma unroll
  for (int kb = 0; kb < 4; ++kb) {
#pragma unroll
    for (int ct = 0; ct < 8; ++ct) {
      int row = 128 + ct * 16 + l;  // Wr row (s=1)
      half8_t bf = *(const half8_t*)&Ws[(size_t)row * 128 + (((kb * 4 + g) ^ (l & 7)) * 8)];
      acc[ct] = __builtin_amdgcn_mfma_f32_16x16x32_f16(afH[kb], bf, acc[ct], 0, 0, 0);
    }
  }

#pragma unroll
  for (int ct = 0; ct < 8; ++ct) {
    int col = ct * 16 + l;
    float bc = bias[col];
#pragma unroll
    for (int r = 0; r < 4; ++r) {
      int row = m0 + g * 4 + r;
      if (row < n) {
        float v = fmaxf(acc[ct][r] + bc, 0.f);
        outh[(size_t)row * 128 + col] = (_Float16)v;
      }
    }
  }
}

// ---------------- head GEMM: [n,16] = h3 @ Wcat^T + bcat, split outputs ----------------

__global__ __launch_bounds__(256) void head_gemm_k(const _Float16* __restrict__ h,
                                                   const _Float16* __restrict__ Wcat,
                                                   const float* __restrict__ bcat,
                                                   float* __restrict__ head_g,
                                                   float* __restrict__ head_r, int n) {
  __shared__ _Float16 Ws[2048];  // 16 rows x 128, kc swizzled
  __shared__ float bs[16];
  int tid = threadIdx.x;
  {
    int row = tid >> 4, kc = tid & 15;  // 256 threads = 16x16 chunks exactly
    float4 v = *(const float4*)&Wcat[(size_t)row * 128 + kc * 8];
    *(float4*)&Ws[(size_t)row * 128 + ((kc ^ (row & 7)) * 8)] = v;
    if (tid < 16) bs[tid] = bcat[tid];
  }
  __syncthreads();
  int wave = tid >> 6;
  int lane = tid & 63;
  int g = lane >> 4;
  int l = lane & 15;
  int m0 = blockIdx.x * 64 + wave * 16;
  int arow = m0 + l;
  bool valid = arow < n;
  size_t abase = (size_t)arow * 128 + g * 8;
  f32x4 acc = (f32x4){0.f, 0.f, 0.f, 0.f};
#pragma unroll
  for (int kb = 0; kb < 4; ++kb) {
    half8_t af;
    if (valid) {
      af = *(const half8_t*)&h[abase + kb * 32];
    } else {
#pragma unroll
      for (int jj = 0; jj < 8; ++jj) af[jj] = (_Float16)0;
    }
    half8_t bf = *(const half8_t*)&Ws[(size_t)l * 128 + (((kb * 4 + g) ^ (l & 7)) * 8)];
    acc = __builtin_amdgcn_mfma_f32_16x16x32_f16(af, bf, acc, 0, 0, 0);
  }
  float bc = bs[l];
#pragma unroll
  for (int r = 0; r < 4; ++r) {
    int row = m0 + g * 4 + r;
    if (row < n) {
      float v = acc[r] + bc;
      if (l < 8) head_g[(size_t)row * 8 + l] = v;
      else head_r[(size_t)row * 8 + (l - 8)] = v;
    }
  }
}

// ---------------- 8-dim aggregation + output write ----------------
// out layout: age [n,3] @0, sex [n,2] @3n, eth [n,3] @5n

__global__ void agg8_k(const float* __restrict__ head_g, const float* __restrict__ head_r,
                       const int* __restrict__ csr, const int* __restrict__ row_start,
                       const int* __restrict__ deg, const float* __restrict__ invd,
                       float* __restrict__ out, int n) {
  int node = (blockIdx.x << 2) + (threadIdx.x >> 6);
  if (node >= n) return;
  int lane = threadIdx.x & 63;
  int c2 = lane & 3;  // feature pair
  int g = lane >> 2;  // edge slot 0..15
  int s = row_start[node], cnt = deg[node];
  float ax = 0.f, ay = 0.f;
  int j = 0;
  for (; j + 32 <= cnt; j += 32) {
#pragma unroll
    for (int p = 0; p < 2; ++p) {
      int id = csr[s + j + 16 * p + g];
      float2 v = *(const float2*)&head_g[(size_t)id * 8 + 2 * c2];
      ax += v.x;
      ay += v.y;
    }
  }
  if (j < cnt) {
    int cm1 = cnt - 1;
#pragma unroll
    for (int p = 0; p < 2; ++p) {
      int e = j + 16 * p + g;
      float m = (e < cnt) ? 1.f : 0.f;
      int id = csr[s + min(e, cm1)];
      float2 v = *(const float2*)&head_g[(size_t)id * 8 + 2 * c2];
      ax = fmaf(m, v.x, ax);
      ay = fmaf(m, v.y, ay);
    }
  }
  ax += __shfl_xor(ax, 4);  ay += __shfl_xor(ay, 4);
  ax += __shfl_xor(ax, 8);  ay += __shfl_xor(ay, 8);
  ax += __shfl_xor(ax, 16); ay += __shfl_xor(ay, 16);
  ax += __shfl_xor(ax, 32); ay += __shfl_xor(ay, 32);
  if (g == 0) {
    float w = invd[node];
    float r0 = ax * w + head_r[(size_t)node * 8 + 2 * c2];
    float r1 = ay * w + head_r[(size_t)node * 8 + 2 * c2 + 1];
    float rr[2] = {r0, r1};
#pragma unroll
    for (int q = 0; q < 2; ++q) {
      int f = 2 * c2 + q;
      float r = rr[q];
      if (f < 3) out[(size_t)node * 3 + f] = r;
      else if (f < 5) out[(size_t)3 * n + (size_t)node * 2 + (f - 3)] = r;
      else out[(size_t)5 * n + (size_t)node * 3 + (f - 5)] = r;
    }
  }
}

// ---------------- launch ----------------

extern "C" void kernel_launch(void* const* d_in, const int* in_sizes, int n_in,
                              void* d_out, int out_size, void* d_ws, size_t ws_size,
                              hipStream_t stream) {
  const float* x = (const float*)d_in[0];
  const int* ei = (const int*)d_in[1];
  const float* W1l = (const float*)d_in[2];
  const float* W1r = (const float*)d_in[3];
  const float* b1 = (const float*)d_in[4];
  const float* W2l = (const float*)d_in[5];
  const float* W2r = (const float*)d_in[6];
  const float* b2 = (const float*)d_in[7];
  const float* W3l = (const float*)d_in[8];
  const float* W3r = (const float*)d_in[9];
  const float* b3 = (const float*)d_in[10];
  const float* Wal = (const float*)d_in[11];
  const float* War = (const float*)d_in[12];
  const float* ba = (const float*)d_in[13];
  const float* Wsl = (const float*)d_in[14];
  const float* Wsr = (const float*)d_in[15];
  const float* bsx = (const float*)d_in[16];
  const float* Wel = (const float*)d_in[17];
  const float* Wer = (const float*)d_in[18];
  const float* be = (const float*)d_in[19];

  int N = in_sizes[0] / 128;
  int E = in_sizes[1] / 2;
  int NBKT = (N + 255) >> 8;

  char* w = (char*)d_ws;
  auto alloc = [&](size_t b) {
    char* p = w;
    w += (b + 255) & ~(size_t)255;
    return p;
  };
  int* deg = (int*)alloc((size_t)N * 4);
  int* row_start = (int*)alloc((size_t)N * 4);
  float* invd = (float*)alloc((size_t)N * 4);
  int* hist = (int*)alloc((size_t)NBUCK * NB1 * 4);
  int* chunk = (int*)alloc(2048 * 4);
  int* csr = (int*)alloc((size_t)E * 4);
  // xh (fp16 x, N*128*2 B) aliases ebuf (E*4 B): ebuf dead after build_k.
  size_t xh_bytes = (size_t)N * 128 * 2;
  size_t ebuf_bytes = (size_t)E * 4;
  char* region = (char*)alloc(xh_bytes > ebuf_bytes ? xh_bytes : ebuf_bytes);
  unsigned* ebuf = (unsigned*)region;
  _Float16* xh = (_Float16*)region;
  _Float16* aggh = (_Float16*)alloc((size_t)N * 128 * 2);
  _Float16* hA = (_Float16*)alloc((size_t)N * 128 * 2);
  _Float16* hB = (_Float16*)alloc((size_t)N * 128 * 2);
  _Float16* wh = (_Float16*)alloc((size_t)6 * 16384 * 2);
  _Float16* Wcat = (_Float16*)alloc(2048 * 2);
  float* bcat = (float*)alloc(16 * 4);
  float* head_g = (float*)alloc((size_t)N * 8 * 4);
  float* head_r = (float*)alloc((size_t)N * 8 * 4);

  int stripe = (((E + NB1 - 1) / NB1) + 255) & ~255;
  int nscan = NBUCK * NB1;
  int nbScan = (nscan + TPB - 1) / TPB;  // 2048 <= scan2 capacity
  int nbNode = (N + 3) / 4;
  int nbM = (N + 63) / 64;
  int nbC = (N * 32 + TPB - 1) / TPB;

  // CSR build — no global atomics
  hist1_k<<<NB1, 256, 0, stream>>>(ei, hist, E, stripe);
  scan1_k<<<nbScan, TPB, 0, stream>>>(hist, hist, chunk, nscan);
  scan2_k<<<1, 512, 0, stream>>>(chunk, nbScan);
  scan3_k<<<nbScan, TPB, 0, stream>>>(hist, chunk, nscan);
  scatter1_k<<<NB1, 256, 0, stream>>>(ei, hist, ebuf, E, stripe);
  build_k<<<NBKT, 512, 0, stream>>>(ebuf, hist, row_start, deg, invd, csr, N, E);

  // conversions + packing (xh aliases ebuf: after build_k)
  prep_k<<<nbC, TPB, 0, stream>>>(x, xh, N * 32, W1l, W1r, W2l, W2r, W3l, W3r, wh,
                                  Wal, War, ba, Wsl, Wsr, bsx, Wel, Wer, be, Wcat, bcat);

  // layer 1: x -> hA
  agg128_k<<<nbNode, TPB, 0, stream>>>(xh, csr, row_start, deg, invd, aggh, N);
  gemm2_k<<<nbM, TPB, 0, stream>>>(aggh, xh, wh + 0 * 16384, b1, hA, N);
  // layer 2: hA -> hB
  agg128_k<<<nbNode, TPB, 0, stream>>>(hA, csr, row_start, deg, invd, aggh, N);
  gemm2_k<<<nbM, TPB, 0, stream>>>(aggh, hA, wh + 2 * 16384, b2, hB, N);
  // layer 3: hB -> hA
  agg128_k<<<nbNode, TPB, 0, stream>>>(hB, csr, row_start, deg, invd, aggh, N);
  gemm2_k<<<nbM, TPB, 0, stream>>>(aggh, hB, wh + 4 * 16384, b3, hA, N);
  // heads: transform to split 8+8 layout, then aggregate
  head_gemm_k<<<nbM, TPB, 0, stream>>>(hA, Wcat, bcat, head_g, head_r, N);
  agg8_k<<<nbNode, TPB, 0, stream>>>(head_g, head_r, csr, row_start, deg, invd,
                                     (float*)d_out, N);
}

// Round 13
// 656.192 us; speedup vs baseline: 1.4819x; 1.0426x over previous
//
#include <hip/hip_runtime.h>

#define TPB 256
#define NB1 256    // stripe blocks for edge passes (R12: widening is NULL — write-scatter-bound)
#define NBUCK 512  // coarse buckets (dst>>8); supports N <= 131072

using half4_t = __attribute__((ext_vector_type(4))) _Float16;
using half8_t = __attribute__((ext_vector_type(8))) _Float16;
using f32x4 = __attribute__((ext_vector_type(4))) float;

// ---------------- hist + prep fused: block-range split ----------------
// First NB1 blocks: MSD histogram of dst>>8 (narrow, LDS-atomic).
// Remaining blocks: f2h(x) + weight converts + head pack (wide, fills the
// machine while the hist stripe runs). xh no longer aliases ebuf.

__global__ __launch_bounds__(256) void histprep_k(
    const int* __restrict__ ei, int* __restrict__ hist, int E, int stripe,
    const float* __restrict__ x, _Float16* __restrict__ xh, int n4,
    const float* __restrict__ w0, const float* __restrict__ w1,
    const float* __restrict__ w2, const float* __restrict__ w3,
    const float* __restrict__ w4, const float* __restrict__ w5,
    _Float16* __restrict__ wh,
    const float* __restrict__ Wal, const float* __restrict__ War,
    const float* __restrict__ ba, const float* __restrict__ Wsl,
    const float* __restrict__ Wsr, const float* __restrict__ bsx,
    const float* __restrict__ Wel, const float* __restrict__ Wer,
    const float* __restrict__ be, _Float16* __restrict__ Wcat,
    float* __restrict__ bcat) {
  __shared__ int h[NBUCK];
  int b = blockIdx.x;
  if (b < NB1) {
    for (int i = threadIdx.x; i < NBUCK; i += 256) h[i] = 0;
    __syncthreads();
    int b0 = b * stripe;
    int b1 = min(b0 + stripe, E);
    for (int e = b0 + threadIdx.x; e < b1; e += 256) atomicAdd(&h[ei[E + e] >> 8], 1);
    __syncthreads();
    for (int i = threadIdx.x; i < NBUCK; i += 256) hist[i * NB1 + b] = h[i];
    return;
  }
  int t = (b - NB1) * TPB + threadIdx.x;
  if (t < n4) {
    float4 v = ((const float4*)x)[t];
    half4_t o;
    o.x = (_Float16)v.x; o.y = (_Float16)v.y; o.z = (_Float16)v.z; o.w = (_Float16)v.w;
    ((half4_t*)xh)[t] = o;
  }
  if (t < 6 * 4096) {
    int which = t >> 12, i = t & 4095;
    const float* src = which == 0 ? w0 : which == 1 ? w1 : which == 2 ? w2
                     : which == 3 ? w3 : which == 4 ? w4 : w5;
    float4 v = ((const float4*)src)[i];
    half4_t o;
    o.x = (_Float16)v.x; o.y = (_Float16)v.y; o.z = (_Float16)v.z; o.w = (_Float16)v.w;
    ((half4_t*)wh)[(size_t)which * 4096 + i] = o;
  }
  if (t < 2048) {
    float v = 0.f;
    if (t < 384) v = Wal[t];
    else if (t < 640) v = Wsl[t - 384];
    else if (t < 1024) v = Wel[t - 640];
    else if (t < 1408) v = War[t - 1024];
    else if (t < 1664) v = Wsr[t - 1408];
    else v = Wer[t - 1664];
    Wcat[t] = (_Float16)v;
  }
  if (t < 16) {
    float bb = 0.f;
    if (t >= 8 && t < 11) bb = ba[t - 8];
    else if (t >= 11 && t < 13) bb = bsx[t - 11];
    else if (t >= 13) bb = be[t - 13];
    bcat[t] = bb;
  }
}

__global__ void scan1_k(const int* __restrict__ src, int* __restrict__ out,
                        int* __restrict__ chunk, int n) {
  __shared__ int sh[TPB];
  int i = blockIdx.x * TPB + threadIdx.x;
  int v = (i < n) ? src[i] : 0;
  sh[threadIdx.x] = v;
  __syncthreads();
  for (int off = 1; off < TPB; off <<= 1) {
    int t = (threadIdx.x >= off) ? sh[threadIdx.x - off] : 0;
    __syncthreads();
    sh[threadIdx.x] += t;
    __syncthreads();
  }
  if (i < n) out[i] = sh[threadIdx.x] - v;
  if (threadIdx.x == TPB - 1) chunk[blockIdx.x] = sh[TPB - 1];
}

__global__ void scan2_k(int* __restrict__ chunk, int nb) {
  __shared__ int sh[512];
  int v = (threadIdx.x < nb) ? chunk[threadIdx.x] : 0;
  sh[threadIdx.x] = v;
  __syncthreads();
  for (int off = 1; off < 512; off <<= 1) {
    int t = (threadIdx.x >= off) ? sh[threadIdx.x - off] : 0;
    __syncthreads();
    sh[threadIdx.x] += t;
    __syncthreads();
  }
  if (threadIdx.x < nb) chunk[threadIdx.x] = sh[threadIdx.x] - v;
}

// scan3 eliminated: with NB1==256, element i*256+b lives in chunk block i, so
// consumers add chunk[] at read time (scatter1: +chunk[i]; build: +chunk[b]).

// pack: src (24 bits) | low8(dst) << 24
__global__ __launch_bounds__(256) void scatter1_k(const int* __restrict__ ei,
                                                  const int* __restrict__ base,
                                                  const int* __restrict__ chunk,
                                                  unsigned* __restrict__ ebuf, int E,
                                                  int stripe) {
  __shared__ int cur[NBUCK];
  for (int i = threadIdx.x; i < NBUCK; i += 256)
    cur[i] = base[i * NB1 + blockIdx.x] + chunk[i];
  __syncthreads();
  int b0 = blockIdx.x * stripe;
  int b1 = min(b0 + stripe, E);
  for (int e = b0 + threadIdx.x; e < b1; e += 256) {
    int s = ei[e];
    int d = ei[E + e];
    int p = atomicAdd(&cur[d >> 8], 1);
    ebuf[p] = (unsigned)s | ((unsigned)(d & 255) << 24);
  }
}

__global__ __launch_bounds__(256) void build_k(const unsigned* __restrict__ ebuf,
                                               const int* __restrict__ base,
                                               const int* __restrict__ chunk,
                                               int* __restrict__ row_start,
                                               int* __restrict__ deg,
                                               float* __restrict__ invd,
                                               int* __restrict__ csr, int N, int E) {
  __shared__ int h[256];
  __shared__ int excl[256];
  __shared__ int bse[2];
  int b = blockIdx.x;
  int t = threadIdx.x;
  if (t == 0) {
    bse[0] = base[b * NB1] + chunk[b];
    bse[1] = (b + 1 < NBUCK) ? base[(b + 1) * NB1] + chunk[b + 1] : E;
  }
  h[t] = 0;
  __syncthreads();
  int bs = bse[0], be = bse[1];
  for (int e = bs + t; e < be; e += 256) atomicAdd(&h[ebuf[e] >> 24], 1);
  __syncthreads();
  int v = h[t];
  excl[t] = v;
  __syncthreads();
  for (int off = 1; off < 256; off <<= 1) {
    int tv = (t >= off) ? excl[t - off] : 0;
    __syncthreads();
    excl[t] += tv;
    __syncthreads();
  }
  int ex = excl[t] - v;
  int node = b * 256 + t;
  if (node < N) {
    row_start[node] = bs + ex;
    deg[node] = v;
    invd[node] = 1.0f / fmaxf((float)v, 1.0f);
  }
  h[t] = bs + ex;
  __syncthreads();
  for (int e = bs + t; e < be; e += 256) {
    unsigned p = ebuf[e];
    int pos = atomicAdd(&h[p >> 24], 1);
    csr[pos] = (int)(p & 0xFFFFFFu);
  }
}

// ---------------- 128-dim mean aggregation (R1/R8-verified: ~104us, 75% occ) ----------------
// At the CU vector-memory request/delivery roofline (R9 planar null: time
// tracks 64B-line request count, which is E*4/layer irreducible at fp16).

__global__ __launch_bounds__(256) void agg128_k(const _Float16* __restrict__ hb,
                                                const int* __restrict__ csr,
                                                const int* __restrict__ row_start,
                                                const int* __restrict__ deg,
                                                const float* __restrict__ invd,
                                                _Float16* __restrict__ out, int n) {
  int node = (blockIdx.x << 2) + (threadIdx.x >> 6);
  if (node >= n) return;
  int lane = threadIdx.x & 63;
  int g = lane >> 4;  // edge slot 0..3
  int l = lane & 15;  // feature lane
  int s = row_start[node];
  int c = deg[node];
  const _Float16* base = hb + (l << 3);
  float a0 = 0.f, a1 = 0.f, a2 = 0.f, a3 = 0.f;
  float a4 = 0.f, a5 = 0.f, a6 = 0.f, a7 = 0.f;
  int j = 0;
  if (c >= 16) {
    int id[4];
#pragma unroll
    for (int p = 0; p < 4; ++p) id[p] = csr[s + 4 * p + g];
    while (true) {
      half8_t v[4];
#pragma unroll
      for (int p = 0; p < 4; ++p) v[p] = *(const half8_t*)&base[(size_t)id[p] * 128];
      j += 16;
      bool more = (j + 16 <= c);
      if (more) {
#pragma unroll
        for (int p = 0; p < 4; ++p) id[p] = csr[s + j + 4 * p + g];
      }
#pragma unroll
      for (int p = 0; p < 4; ++p) {
        a0 += (float)v[p][0]; a1 += (float)v[p][1];
        a2 += (float)v[p][2]; a3 += (float)v[p][3];
        a4 += (float)v[p][4]; a5 += (float)v[p][5];
        a6 += (float)v[p][6]; a7 += (float)v[p][7];
      }
      if (!more) break;
    }
  }
  if (j < c) {  // masked tail: 0..15 edges, all loads issued together
    int cm1 = c - 1;
#pragma unroll
    for (int p = 0; p < 4; ++p) {
      int e = j + 4 * p + g;
      float m = (e < c) ? 1.f : 0.f;
      int id = csr[s + min(e, cm1)];
      half8_t v = *(const half8_t*)&base[(size_t)id * 128];
      a0 = fmaf(m, (float)v[0], a0); a1 = fmaf(m, (float)v[1], a1);
      a2 = fmaf(m, (float)v[2], a2); a3 = fmaf(m, (float)v[3], a3);
      a4 = fmaf(m, (float)v[4], a4); a5 = fmaf(m, (float)v[5], a5);
      a6 = fmaf(m, (float)v[6], a6); a7 = fmaf(m, (float)v[7], a7);
    }
  }
  // reduce across the 4 edge slots (lanes l, l+16, l+32, l+48)
  a0 += __shfl_xor(a0, 16); a1 += __shfl_xor(a1, 16);
  a2 += __shfl_xor(a2, 16); a3 += __shfl_xor(a3, 16);
  a4 += __shfl_xor(a4, 16); a5 += __shfl_xor(a5, 16);
  a6 += __shfl_xor(a6, 16); a7 += __shfl_xor(a7, 16);
  a0 += __shfl_xor(a0, 32); a1 += __shfl_xor(a1, 32);
  a2 += __shfl_xor(a2, 32); a3 += __shfl_xor(a3, 32);
  a4 += __shfl_xor(a4, 32); a5 += __shfl_xor(a5, 32);
  a6 += __shfl_xor(a6, 32); a7 += __shfl_xor(a7, 32);
  if (g == 0) {
    float w = invd[node];
    half8_t r;
    r[0] = (_Float16)(a0 * w); r[1] = (_Float16)(a1 * w);
    r[2] = (_Float16)(a2 * w); r[3] = (_Float16)(a3 * w);
    r[4] = (_Float16)(a4 * w); r[5] = (_Float16)(a5 * w);
    r[6] = (_Float16)(a6 * w); r[7] = (_Float16)(a7 * w);
    *(half8_t*)&out[(size_t)node * 128 + (l << 3)] = r;
  }
}

// ---------------- dense dual GEMM: weights in LDS (XOR-swizzled), 64-row blocks ----------------
// mode 0: outh = relu(Aagg@Wl^T + Ah@Wr^T + b) -> fp16 [n][128].
// mode 1 (layer 3 + heads fused): h3 kept on-chip — after the main MFMAs +
// barrier, each wave stages relu(h3) into its (now-dead) quarter of Ws, then
// head-MFMAs vs Wcat (global, 2 KB, L2-hot) and writes split head outputs:
// head_g[n][8] (gathered part, 32 B rows for agg8) + head_r[n][8] (root).
// Saves the head_gemm dispatch AND the 51 MB hA write+read round-trip.

__global__ __launch_bounds__(256) void gemm2_k(
    const _Float16* __restrict__ Aagg, const _Float16* __restrict__ Ah,
    const _Float16* __restrict__ Wh,  // [2][128][128]: Wl then Wr
    const float* __restrict__ bias, _Float16* __restrict__ outh,
    const _Float16* __restrict__ Wcat, const float* __restrict__ bcat,
    float* __restrict__ head_g, float* __restrict__ head_r, int n, int mode) {
  __shared__ _Float16 Ws[32768];  // 64 KB: [row 0..255][k 0..127], kc swizzled
  int tid = threadIdx.x;
  int wave = tid >> 6;
  int lane = tid & 63;
  int g = lane >> 4;
  int l = lane & 15;
  int m0 = blockIdx.x * 64 + wave * 16;
  int arow = m0 + l;
  bool valid = arow < n;

  // prefetch A fragments (issue before staging so HBM latency hides under it)
  half8_t afA[4], afH[4];
  size_t abase = (size_t)arow * 128 + g * 8;
  if (valid) {
#pragma unroll
    for (int kb = 0; kb < 4; ++kb) afA[kb] = *(const half8_t*)&Aagg[abase + kb * 32];
#pragma unroll
    for (int kb = 0; kb < 4; ++kb) afH[kb] = *(const half8_t*)&Ah[abase + kb * 32];
  } else {
#pragma unroll
    for (int kb = 0; kb < 4; ++kb) {
#pragma unroll
      for (int jj = 0; jj < 8; ++jj) { afA[kb][jj] = (_Float16)0; afH[kb][jj] = (_Float16)0; }
    }
  }

  // stage weights: 256 rows x 16 chunks of 16 B; chunk kc stored at kc^(row&7)
#pragma unroll
  for (int it = 0; it < 16; ++it) {
    int ci = tid + it * 256;        // 0..4095
    int row = ci >> 4;              // 0..255 (s*128+col)
    int kc = ci & 15;
    float4 v = *(const float4*)&Wh[(size_t)row * 128 + kc * 8];
    *(float4*)&Ws[(size_t)row * 128 + ((kc ^ (row & 7)) * 8)] = v;
  }
  __syncthreads();

  f32x4 acc[8];
#pragma unroll
  for (int ct = 0; ct < 8; ++ct) acc[ct] = (f32x4){0.f, 0.f, 0.f, 0.f};

#pragma unroll
  for (int kb = 0; kb < 4; ++kb) {
#pragma unroll
    for (int ct = 0; ct < 8; ++ct) {
      int row = ct * 16 + l;  // Wl row (s=0)
      half8_t bf = *(const half8_t*)&Ws[(size_t)row * 128 + (((kb * 4 + g) ^ (l & 7)) * 8)];
      acc[ct] = __builtin_amdgcn_mfma_f32_16x16x32_f16(afA[kb], bf, acc[ct], 0, 0, 0);
    }
  }
#pragma unroll
  for (int kb = 0; kb < 4; ++kb) {
#pragma unroll
    for (int ct = 0; ct < 8; ++ct) {
      int row = 128 + ct * 16 + l;  // Wr row (s=1)
      half8_t bf = *(const half8_t*)&Ws[(size_t)row * 128 + (((kb * 4 + g) ^ (l & 7)) * 8)];
      acc[ct] = __builtin_amdgcn_mfma_f32_16x16x32_f16(afH[kb], bf, acc[ct], 0, 0, 0);
    }
  }

  if (mode == 0) {
#pragma unroll
    for (int ct = 0; ct < 8; ++ct) {
      int col = ct * 16 + l;
      float bc = bias[col];
#pragma unroll
      for (int r = 0; r < 4; ++r) {
        int row = m0 + g * 4 + r;
        if (row < n) {
          float v = fmaxf(acc[ct][r] + bc, 0.f);
          outh[(size_t)row * 128 + col] = (_Float16)v;
        }
      }
    }
  } else {
    // all waves done reading weights before any overwrite
    __syncthreads();
    _Float16* Hs = Ws + wave * 2048;  // wave-private 16x128 h3 strip
#pragma unroll
    for (int ct = 0; ct < 8; ++ct) {
      int col = ct * 16 + l;
      float bc = bias[col];
#pragma unroll
      for (int r = 0; r < 4; ++r) {
        Hs[(g * 4 + r) * 128 + col] = (_Float16)fmaxf(acc[ct][r] + bc, 0.f);
      }
    }
    // same-wave LDS writes/reads are in order: no barrier needed
    f32x4 ah = (f32x4){0.f, 0.f, 0.f, 0.f};
#pragma unroll
    for (int kb = 0; kb < 4; ++kb) {
      half8_t af = *(const half8_t*)&Hs[l * 128 + kb * 32 + g * 8];
      half8_t bf = *(const half8_t*)&Wcat[(size_t)l * 128 + kb * 32 + g * 8];
      ah = __builtin_amdgcn_mfma_f32_16x16x32_f16(af, bf, ah, 0, 0, 0);
    }
    float bc = bcat[l];
#pragma unroll
    for (int r = 0; r < 4; ++r) {
      int row = m0 + g * 4 + r;
      if (row < n) {
        float v = ah[r] + bc;
        if (l < 8) head_g[(size_t)row * 8 + l] = v;
        else head_r[(size_t)row * 8 + (l - 8)] = v;
      }
    }
  }
}

// ---------------- 8-dim aggregation + output write ----------------
// out layout: age [n,3] @0, sex [n,2] @3n, eth [n,3] @5n

__global__ void agg8_k(const float* __restrict__ head_g, const float* __restrict__ head_r,
                       const int* __restrict__ csr, const int* __restrict__ row_start,
                       const int* __restrict__ deg, const float* __restrict__ invd,
                       float* __restrict__ out, int n) {
  int node = (blockIdx.x << 2) + (threadIdx.x >> 6);
  if (node >= n) return;
  int lane = threadIdx.x & 63;
  int c2 = lane & 3;  // feature pair
  int g = lane >> 2;  // edge slot 0..15
  int s = row_start[node], cnt = deg[node];
  float ax = 0.f, ay = 0.f;
  int j = 0;
  for (; j + 32 <= cnt; j += 32) {
#pragma unroll
    for (int p = 0; p < 2; ++p) {
      int id = csr[s + j + 16 * p + g];
      float2 v = *(const float2*)&head_g[(size_t)id * 8 + 2 * c2];
      ax += v.x;
      ay += v.y;
    }
  }
  if (j < cnt) {
    int cm1 = cnt - 1;
#pragma unroll
    for (int p = 0; p < 2; ++p) {
      int e = j + 16 * p + g;
      float m = (e < cnt) ? 1.f : 0.f;
      int id = csr[s + min(e, cm1)];
      float2 v = *(const float2*)&head_g[(size_t)id * 8 + 2 * c2];
      ax = fmaf(m, v.x, ax);
      ay = fmaf(m, v.y, ay);
    }
  }
  ax += __shfl_xor(ax, 4);  ay += __shfl_xor(ay, 4);
  ax += __shfl_xor(ax, 8);  ay += __shfl_xor(ay, 8);
  ax += __shfl_xor(ax, 16); ay += __shfl_xor(ay, 16);
  ax += __shfl_xor(ax, 32); ay += __shfl_xor(ay, 32);
  if (g == 0) {
    float w = invd[node];
    float r0 = ax * w + head_r[(size_t)node * 8 + 2 * c2];
    float r1 = ay * w + head_r[(size_t)node * 8 + 2 * c2 + 1];
    float rr[2] = {r0, r1};
#pragma unroll
    for (int q = 0; q < 2; ++q) {
      int f = 2 * c2 + q;
      float r = rr[q];
      if (f < 3) out[(size_t)node * 3 + f] = r;
      else if (f < 5) out[(size_t)3 * n + (size_t)node * 2 + (f - 3)] = r;
      else out[(size_t)5 * n + (size_t)node * 3 + (f - 5)] = r;
    }
  }
}

// ---------------- launch ----------------

extern "C" void kernel_launch(void* const* d_in, const int* in_sizes, int n_in,
                              void* d_out, int out_size, void* d_ws, size_t ws_size,
                              hipStream_t stream) {
  const float* x = (const float*)d_in[0];
  const int* ei = (const int*)d_in[1];
  const float* W1l = (const float*)d_in[2];
  const float* W1r = (const float*)d_in[3];
  const float* b1 = (const float*)d_in[4];
  const float* W2l = (const float*)d_in[5];
  const float* W2r = (const float*)d_in[6];
  const float* b2 = (const float*)d_in[7];
  const float* W3l = (const float*)d_in[8];
  const float* W3r = (const float*)d_in[9];
  const float* b3 = (const float*)d_in[10];
  const float* Wal = (const float*)d_in[11];
  const float* War = (const float*)d_in[12];
  const float* ba = (const float*)d_in[13];
  const float* Wsl = (const float*)d_in[14];
  const float* Wsr = (const float*)d_in[15];
  const float* bsx = (const float*)d_in[16];
  const float* Wel = (const float*)d_in[17];
  const float* Wer = (const float*)d_in[18];
  const float* be = (const float*)d_in[19];

  int N = in_sizes[0] / 128;
  int E = in_sizes[1] / 2;
  int NBKT = (N + 255) >> 8;

  char* w = (char*)d_ws;
  auto alloc = [&](size_t b) {
    char* p = w;
    w += (b + 255) & ~(size_t)255;
    return p;
  };
  int* deg = (int*)alloc((size_t)N * 4);
  int* row_start = (int*)alloc((size_t)N * 4);
  float* invd = (float*)alloc((size_t)N * 4);
  int* hist = (int*)alloc((size_t)NBUCK * NB1 * 4);
  int* chunk = (int*)alloc(512 * 4);
  int* csr = (int*)alloc((size_t)E * 4);
  unsigned* ebuf = (unsigned*)alloc((size_t)E * 4);
  _Float16* xh = (_Float16*)alloc((size_t)N * 128 * 2);
  _Float16* aggh = (_Float16*)alloc((size_t)N * 128 * 2);
  _Float16* hA = (_Float16*)alloc((size_t)N * 128 * 2);
  _Float16* hB = (_Float16*)alloc((size_t)N * 128 * 2);
  _Float16* wh = (_Float16*)alloc((size_t)6 * 16384 * 2);
  _Float16* Wcat = (_Float16*)alloc(2048 * 2);
  float* bcat = (float*)alloc(16 * 4);
  float* head_g = (float*)alloc((size_t)N * 8 * 4);
  float* head_r = (float*)alloc((size_t)N * 8 * 4);

  int stripe = (((E + NB1 - 1) / NB1) + 255) & ~255;
  int nscan = NBUCK * NB1;
  int nbScan = (nscan + TPB - 1) / TPB;  // 512
  int nbNode = (N + 3) / 4;
  int nbM = (N + 63) / 64;
  int nbC = (N * 32 + TPB - 1) / TPB;

  // hist (narrow) + prep (wide) fused; then scan; scan3 folded into consumers
  histprep_k<<<NB1 + nbC, TPB, 0, stream>>>(ei, hist, E, stripe, x, xh, N * 32,
                                            W1l, W1r, W2l, W2r, W3l, W3r, wh,
                                            Wal, War, ba, Wsl, Wsr, bsx, Wel, Wer,
                                            be, Wcat, bcat);
  scan1_k<<<nbScan, TPB, 0, stream>>>(hist, hist, chunk, nscan);
  scan2_k<<<1, 512, 0, stream>>>(chunk, nbScan);
  scatter1_k<<<NB1, 256, 0, stream>>>(ei, hist, chunk, ebuf, E, stripe);
  build_k<<<NBKT, 256, 0, stream>>>(ebuf, hist, chunk, row_start, deg, invd, csr, N, E);

  // layer 1: x -> hA
  agg128_k<<<nbNode, TPB, 0, stream>>>(xh, csr, row_start, deg, invd, aggh, N);
  gemm2_k<<<nbM, TPB, 0, stream>>>(aggh, xh, wh + 0 * 16384, b1, hA, nullptr, nullptr,
                                   nullptr, nullptr, N, 0);
  // layer 2: hA -> hB
  agg128_k<<<nbNode, TPB, 0, stream>>>(hA, csr, row_start, deg, invd, aggh, N);
  gemm2_k<<<nbM, TPB, 0, stream>>>(aggh, hA, wh + 2 * 16384, b2, hB, nullptr, nullptr,
                                   nullptr, nullptr, N, 0);
  // layer 3 + heads fused: hB -> head_g/head_r (h3 never hits HBM)
  agg128_k<<<nbNode, TPB, 0, stream>>>(hB, csr, row_start, deg, invd, aggh, N);
  gemm2_k<<<nbM, TPB, 0, stream>>>(aggh, hB, wh + 4 * 16384, b3, nullptr, Wcat, bcat,
                                   head_g, head_r, N, 1);
  // final 8-dim neighbor aggregation + output
  agg8_k<<<nbNode, TPB, 0, stream>>>(head_g, head_r, csr, row_start, deg, invd,
                                     (float*)d_out, N);
}